// Round 1
// baseline (195.779 us; speedup 1.0000x reference)
//
#include <hip/hip_runtime.h>

#define NN      20
#define FF      2764800            // 3*720*1280
#define TK      128                // k-tile (floats)
#define NROWS   40                 // 20 rows clip2 + 20 rows clip1
#define NTILES  (FF / TK)          // 21600
#define GRID    768                // 3 blocks/CU * 256 CUs
#define NTHREADS 256

// ws layout (floats): [0..399] cross[i*20+j] = c2[i].c1[j]
//                     [400..419] q2[i] = c2[i].c2[i]
//                     [420..439] q1[j] = c1[j].c1[j]

__global__ void zero_ws_kernel(float* __restrict__ ws) {
    int i = threadIdx.x;
    if (i < 440) ws[i] = 0.0f;
}

__global__ __launch_bounds__(NTHREADS, 3) void gram_kernel(
    const float* __restrict__ clip1,
    const float* __restrict__ clip2,
    float* __restrict__ ws)
{
    __shared__ float s[NROWS][TK];          // 20,480 B

    const int tid   = threadIdx.x;
    const int slice = tid >> 3;             // 0..31  == k-chunk index within tile
    const int sub   = tid & 7;
    const int gi    = sub >> 2;             // 0..1   (i = gi + 2*ri, ri 0..9)
    const int gj    = sub & 3;              // 0..3   (j = gj + 4*rj, rj 0..4)
    const int k0    = slice * 4;            // float offset of this thread's chunk

    float acc[10][5];
    #pragma unroll
    for (int a = 0; a < 10; ++a)
        #pragma unroll
        for (int b = 0; b < 5; ++b) acc[a][b] = 0.0f;
    float sq[5] = {0.f, 0.f, 0.f, 0.f, 0.f};

    // staging map: idx = tid + 256*r -> row = idx>>5 (0..39), f4 = idx&31
    const float* srow[5];
    int foff[5];
    int rown[5];
    #pragma unroll
    for (int r = 0; r < 5; ++r) {
        int idx = tid + NTHREADS * r;
        int row = idx >> 5;
        rown[r] = row;
        foff[r] = (idx & 31) * 4;
        srow[r] = (row < NN) ? (clip2 + (size_t)row * FF)
                             : (clip1 + (size_t)(row - NN) * FF);
    }

    for (int t = blockIdx.x; t < NTILES; t += gridDim.x) {
        const size_t kb = (size_t)t * TK;
        float4 v[5];
        #pragma unroll
        for (int r = 0; r < 5; ++r)
            v[r] = *(const float4*)(srow[r] + kb + foff[r]);
        #pragma unroll
        for (int r = 0; r < 5; ++r) {
            *(float4*)&s[rown[r]][foff[r]] = v[r];
            sq[r] += v[r].x * v[r].x + v[r].y * v[r].y
                   + v[r].z * v[r].z + v[r].w * v[r].w;
        }
        __syncthreads();

        // a-fragments: clip2 rows (i side), interleaved rows gi + 2*ri
        float4 av[10];
        #pragma unroll
        for (int ri = 0; ri < 10; ++ri)
            av[ri] = *(const float4*)&s[gi + 2 * ri][k0];
        // b side: clip1 rows, one at a time to bound register pressure
        #pragma unroll
        for (int rj = 0; rj < 5; ++rj) {
            float4 bv = *(const float4*)&s[NN + gj + 4 * rj][k0];
            #pragma unroll
            for (int ri = 0; ri < 10; ++ri) {
                acc[ri][rj] += av[ri].x * bv.x;
                acc[ri][rj] += av[ri].y * bv.y;
                acc[ri][rj] += av[ri].z * bv.z;
                acc[ri][rj] += av[ri].w * bv.w;
            }
        }
        __syncthreads();
    }

    // ---- reduce cross partials over slices ----
    // in-wave: lanes with equal (lane&7) share (gi,gj); butterfly over strides 8,16,32
    #pragma unroll
    for (int a = 0; a < 10; ++a)
        #pragma unroll
        for (int b = 0; b < 5; ++b) {
            float vsum = acc[a][b];
            vsum += __shfl_down(vsum, 8);
            vsum += __shfl_down(vsum, 16);
            vsum += __shfl_down(vsum, 32);
            acc[a][b] = vsum;              // valid on lanes 0..7
        }

    float* red = &s[0][0];                 // reuse LDS: 4 waves * 8 subs * 50 = 1600 floats
    const int lane = tid & 63;
    const int wv   = tid >> 6;
    if (lane < 8) {
        #pragma unroll
        for (int a = 0; a < 10; ++a)
            #pragma unroll
            for (int b = 0; b < 5; ++b)
                red[(wv * 8 + lane) * 50 + a * 5 + b] = acc[a][b];
    }
    __syncthreads();

    for (int p = tid; p < 400; p += NTHREADS) {
        int psub = p / 50;                 // 0..7
        int rem  = p % 50;
        int pa   = rem / 5;                // ri 0..9
        int pb   = rem % 5;                // rj 0..4
        float vsum = red[(0 * 8 + psub) * 50 + rem]
                   + red[(1 * 8 + psub) * 50 + rem]
                   + red[(2 * 8 + psub) * 50 + rem]
                   + red[(3 * 8 + psub) * 50 + rem];
        int i = (psub >> 2) + 2 * pa;
        int j = (psub & 3) + 4 * pb;
        atomicAdd(&ws[i * NN + j], vsum);
    }

    // ---- reduce squares: threads in each aligned 32-lane group share a row ----
    #pragma unroll
    for (int r = 0; r < 5; ++r) {
        float vq = sq[r];
        vq += __shfl_down(vq, 16, 32);
        vq += __shfl_down(vq, 8, 32);
        vq += __shfl_down(vq, 4, 32);
        vq += __shfl_down(vq, 2, 32);
        vq += __shfl_down(vq, 1, 32);
        if ((tid & 31) == 0) {
            int row = (tid + NTHREADS * r) >> 5;   // 0..39
            atomicAdd(&ws[400 + row], vq);
        }
    }
}

__global__ void finalize_kernel(const float* __restrict__ ws, float* __restrict__ out) {
    int d = threadIdx.x;
    if (d >= 21) return;
    int k  = d - 10;                    // diagonal offset (col - row)
    int a  = k < 0 ? -k : k;
    int i0 = k < 0 ? -k : 0;
    int L  = NN - a;
    const float invF = 1.0f / (float)FF;
    float sum = 0.0f;
    for (int m = 0; m < L; ++m) {
        int i = i0 + m;
        int j = i + k;
        // q2[i] + q1[j] - 2*cross[i][j]
        sum += ws[400 + i] + ws[420 + j] - 2.0f * ws[i * NN + j];
    }
    out[d] = -(sum * invF / (float)L) * 1e13f;
}

extern "C" void kernel_launch(void* const* d_in, const int* in_sizes, int n_in,
                              void* d_out, int out_size, void* d_ws, size_t ws_size,
                              hipStream_t stream) {
    const float* clip1 = (const float*)d_in[0];
    const float* clip2 = (const float*)d_in[1];
    float* out = (float*)d_out;
    float* ws  = (float*)d_ws;

    zero_ws_kernel<<<1, 512, 0, stream>>>(ws);
    gram_kernel<<<GRID, NTHREADS, 0, stream>>>(clip1, clip2, ws);
    finalize_kernel<<<1, 64, 0, stream>>>(ws, out);
}